// Round 6
// baseline (20288.777 us; speedup 1.0000x reference)
//
#include <hip/hip_runtime.h>
#include <hip/hip_fp16.h>
#include <cstdint>
#include <cstddef>

// ---------------------------------------------------------------------------
// EnDeModel: GRU encoder (365 steps) -> GRU decoder (90 steps) -> SIRD rollout
// Persistent-grid: 256 WGs x 512 threads (8 waves). Wave w of WG g owns hidden
// unit j = g*8+w (3 enc fp32 rows / 6 dec bf16 rows in registers).
//
// R11: COUNTER-GATED handoff (signal separated from data).
// Evidence: R7 (sticky) neutral, R10 (16 replicas) regressed => limiter is
// TOTAL MALL request rate of per-word polling (~262K req/sweep, ~1.3M/step ~=
// 10K cy at ~128 req/cy -- matches the measured 8.6K cy/step), not per-line
// pile-up. So: producers store packed fp16x4 data ONCE (512 u64 words, 4
// replicas, contiguous 16B per WG -- R9 proved scatter is fatal), then
// __threadfence() (release) + ONE atomicAdd per WG to 1 of 16 line-separated
// counters. Consumers poll ONLY the counters (lanes 0-15, ~32K req/sweep
// grid-wide, 40x less), __threadfence() (acquire), then bulk-read the 4KB
// vector one-shot with agent-scope loads (no tags, no re-reads).
// Correctness: gate for tag T is cnt[g] >= 16*T for all 16 groups. Induction:
// the first WG to pass gate-T sees every WG's contribution <= T, and
// cnt[g] >= 16T with 16 WGs each <= T forces ALL == T => every WG produced T
// => (program order) every WG finished READING tag T-1 => depth-2 slot reuse
// safe. No false positives; every WG increments every step => no deadlock.
// prep_pq zeroes counters each launch (stream-ordered before persist).
// History: R6 XCD relay X; R7 sticky ~; R9 scatter XX; R10 16-replica X.
// ---------------------------------------------------------------------------

#define HID   2048
#define T_ENC 365
#define F_DEC 90
#define NWG   256
#define NTH   512
#define HSLOT 2048   // u64 per ring slot: 4 replicas x 512 words

// ws layout (4-byte units)
#define WS_P    0        // p[6144]
#define WS_Q    6144     // q[6144]
#define WS_CNT  12288    // u64 cnt[16*8]  (16 counters, 64B apart) = 256 floats
#define WS_HBUF 12544    // u64 hb[2][4][512]  (fp16x4 ring)       = 8192 floats
#define WS_DX0  20736    // u64 dy[4][512]     (raw y, one-shot)   = 4096 floats
#define WS_HST  24832    // __half hstore[90][2048]

typedef unsigned long long u64;

__device__ __forceinline__ float sigm(float x) {
    return 1.0f / (1.0f + __expf(-x));
}
__device__ __forceinline__ float tanh_f(float x) {
    return 1.0f - 2.0f / (1.0f + __expf(2.0f * x));
}
__device__ __forceinline__ unsigned bf16rne(float f) {
    unsigned x = __float_as_uint(f);
    return (x + 0x7fffu + ((x >> 16) & 1u)) >> 16;
}
__device__ __forceinline__ unsigned packbf(float lo, float hi) {
    return bf16rne(lo) | (bf16rne(hi) << 16);
}

__device__ __forceinline__ u64 tld(const u64* p) {
    return __hip_atomic_load((u64*)p, __ATOMIC_RELAXED, __HIP_MEMORY_SCOPE_AGENT);
}
__device__ __forceinline__ void tst(u64* p, u64 v) {
    __hip_atomic_store(p, v, __ATOMIC_RELAXED, __HIP_MEMORY_SCOPE_AGENT);
}
// fp16 x4 packed: lo16=h0, lo-hi16=h1, hi-lo16=h2, hi-hi16=h3
__device__ __forceinline__ u64 pk4(float a, float b, float c, float d) {
    unsigned lo = (unsigned)__half_as_ushort(__float2half(a)) |
                  ((unsigned)__half_as_ushort(__float2half(b)) << 16);
    unsigned hi = (unsigned)__half_as_ushort(__float2half(c)) |
                  ((unsigned)__half_as_ushort(__float2half(d)) << 16);
    return (u64)lo | ((u64)hi << 32);
}

// Poll the 16 line-separated counters until all >= tau*16.
__device__ __forceinline__ void wait_tag(const u64* cnt, unsigned tau) {
    const int lane = threadIdx.x & 63;
    const u64 target = (u64)tau * 16;
    if (__ballot(lane < 16 ? (tld(cnt + lane * 8) >= target) : true) == ~0ull)
        return;
    while (true) {
        __builtin_amdgcn_s_sleep(1);
        if (__ballot(lane < 16 ? (tld(cnt + lane * 8) >= target) : true) ==
            ~0ull)
            return;
    }
}

// One-shot read of 512 packed words -> lds[2048] (thread tid owns word tid).
__device__ __forceinline__ void read_vec(const u64* __restrict__ buf, int tid,
                                         float* __restrict__ lds) {
    u64 w = tld(buf + tid);
    unsigned lo = (unsigned)w, hi = (unsigned)(w >> 32);
    float2 f0 = __half22float2(*(__half2*)&lo);
    float2 f1 = __half22float2(*(__half2*)&hi);
    *reinterpret_cast<float4*>(lds + 4 * tid) =
        make_float4(f0.x, f0.y, f1.x, f1.y);
}

// p[r] = enc_Wih[r,:] @ Wb ; q[r] = enc_Wih[r,:] @ bb + enc_bih[r]
// Block 0 also zeroes the 16 handoff counters (stream-ordered before persist).
__global__ void prep_pq(const float* __restrict__ Wih, const float* __restrict__ Wb,
                        const float* __restrict__ bb, const float* __restrict__ bih,
                        float* __restrict__ p, float* __restrict__ q,
                        u64* __restrict__ cnt) {
    if (blockIdx.x == 0 && threadIdx.x < 128) cnt[threadIdx.x] = 0ull;
    int wave = threadIdx.x >> 6, lane = threadIdx.x & 63;
    int row = blockIdx.x * 4 + wave;
    const float* wr = Wih + (size_t)row * HID;
    float ap = 0.f, aq = 0.f;
    for (int k = lane; k < HID; k += 64) {
        float w = wr[k];
        ap += w * Wb[k];
        aq += w * bb[k];
    }
#pragma unroll
    for (int m = 1; m < 64; m <<= 1) {
        ap += __shfl_xor(ap, m);
        aq += __shfl_xor(aq, m);
    }
    if (lane == 0) {
        p[row] = ap;
        q[row] = aq + bih[row];
    }
}

__global__ __launch_bounds__(NTH, 1) void persist(
    const float* __restrict__ hu, const float* __restrict__ encWhh,
    const float* __restrict__ encBhh, const float* __restrict__ decWih,
    const float* __restrict__ decWhh, const float* __restrict__ decBih,
    const float* __restrict__ decBhh, const float* __restrict__ p,
    const float* __restrict__ q, u64* cnt, u64* hbuf, u64* dy,
    __half* hstore) {
    const int wg = blockIdx.x, tid = threadIdx.x;
    const int wave = tid >> 6, lane = tid & 63;
    const int j = wg * 8 + wave;
    const int myrep = wg & 3;  // 64 WGs share a data replica (one-shot reads)
    u64* mycnt = cnt + (wg & 15) * 8;

    __shared__ float h_lds[HID], x_lds[HID];
    __shared__ float hs_l[8], hy_l[8];
    __shared__ float p_l[24], q_l[24], ebhh[24], dbih[24], dbhh[24];
    __shared__ float u_l[T_ENC];

    // --- LDS preloads (once) ---
    for (int idx = tid; idx < T_ENC; idx += NTH) u_l[idx] = hu[idx];
    if (tid < 24) {
        int g = tid >> 3, jj = tid & 7;
        int r = g * HID + wg * 8 + jj;
        p_l[tid] = p[r];
        q_l[tid] = q[r];
        ebhh[tid] = encBhh[r];
        dbih[tid] = decBih[r];
        dbhh[tid] = decBhh[r];
    }

    // --- encoder Whh rows for unit j -> fp32 registers (3 rows/wave) ---
    float4 We[3][8];
#pragma unroll
    for (int g = 0; g < 3; g++) {
        const float* base = encWhh + (size_t)(g * HID + j) * HID;
#pragma unroll
        for (int i = 0; i < 8; i++)
            We[g][i] = *reinterpret_cast<const float4*>(base + 4 * lane + 256 * i);
    }

    float hcar = 0.f;  // lane0-only: this wave's own h (exact fp32 carry)

    // =========================== encoder: 365 steps =========================
    for (int t = 0; t < T_ENC; t++) {
        if (t == 0) {
            for (int idx = tid; idx < HID; idx += NTH) h_lds[idx] = 0.f;
        } else {
            wait_tag(cnt, (unsigned)t);
            __threadfence();
            read_vec(hbuf + (t & 1) * HSLOT + myrep * 512, tid, h_lds);
        }
        __syncthreads();

        float4 hreg[8];
#pragma unroll
        for (int i = 0; i < 8; i++)
            hreg[i] = *reinterpret_cast<const float4*>(&h_lds[4 * lane + 256 * i]);

        float v0, v1, v2;
        {
            float a0 = 0.f, a1 = 0.f, a2 = 0.f, a3 = 0.f;
            float b0 = 0.f, b1 = 0.f, b2 = 0.f, b3 = 0.f;
            float c0 = 0.f, c1 = 0.f, c2 = 0.f, c3 = 0.f;
#pragma unroll
            for (int i = 0; i < 8; i++) {
                float4 h4 = hreg[i];
                float4 wr_ = We[0][i], wz_ = We[1][i], wc_ = We[2][i];
                a0 += wr_.x * h4.x; a1 += wr_.y * h4.y;
                a2 += wr_.z * h4.z; a3 += wr_.w * h4.w;
                b0 += wz_.x * h4.x; b1 += wz_.y * h4.y;
                b2 += wz_.z * h4.z; b3 += wz_.w * h4.w;
                c0 += wc_.x * h4.x; c1 += wc_.y * h4.y;
                c2 += wc_.z * h4.z; c3 += wc_.w * h4.w;
            }
            v0 = (a0 + a1) + (a2 + a3);
            v1 = (b0 + b1) + (b2 + b3);
            v2 = (c0 + c1) + (c2 + c3);
        }
#pragma unroll
        for (int m = 1; m < 64; m <<= 1) {
            v0 += __shfl_xor(v0, m);
            v1 += __shfl_xor(v1, m);
            v2 += __shfl_xor(v2, m);
        }

        if (lane == 0) {
            float u = u_l[t];
            float gir = u * p_l[wave] + q_l[wave];
            float giz = u * p_l[8 + wave] + q_l[8 + wave];
            float gic = u * p_l[16 + wave] + q_l[16 + wave];
            float r = sigm(gir + v0 + ebhh[wave]);
            float z = sigm(giz + v1 + ebhh[8 + wave]);
            float c = tanh_f(gic + r * (v2 + ebhh[16 + wave]));
            float hp = (1.f - z) * c + z * hcar;
            float hs = sigm(hp);
            hcar = hs;
            hs_l[wave] = hs;
            hy_l[wave] = hp;
        }
        __syncthreads();
        // Publish: packed contiguous data stores, release fence, ONE add/WG.
        if (wave == 0) {
            if (lane < 8) {
                int r = lane >> 1, b = lane & 1;
                u64 v = pk4(hs_l[4 * b], hs_l[4 * b + 1], hs_l[4 * b + 2],
                            hs_l[4 * b + 3]);
                tst(hbuf + ((t + 1) & 1) * HSLOT + r * 512 + wg * 2 + b, v);
                if (t == T_ENC - 1) {
                    u64 y = pk4(hy_l[4 * b], hy_l[4 * b + 1], hy_l[4 * b + 2],
                                hy_l[4 * b + 3]);
                    tst(dy + r * 512 + wg * 2 + b, y);
                }
            }
            __threadfence();
            if (lane == 0)
                __hip_atomic_fetch_add(mycnt, 1ull, __ATOMIC_RELAXED,
                                       __HIP_MEMORY_SCOPE_AGENT);
        }
    }

    // --- decoder Wih+Whh rows for unit j -> packed bf16 (6 rows/wave) ---
    unsigned Wd[6][8][2];
#pragma unroll
    for (int g = 0; g < 6; g++) {
        const float* src = (g < 3)
            ? decWih + (size_t)(g * HID + j) * HID
            : decWhh + (size_t)((g - 3) * HID + j) * HID;
#pragma unroll
        for (int i = 0; i < 8; i++) {
            float4 w = *reinterpret_cast<const float4*>(src + 4 * lane + 256 * i);
            Wd[g][i][0] = packbf(w.x, w.y);
            Wd[g][i][1] = packbf(w.z, w.w);
        }
    }

    // =========================== decoder: 90 steps ==========================
    // hcar (lane0) = sigm(hp_365) = h_enc, the decoder's initial hidden state
    for (int s = 0; s < F_DEC; s++) {
        unsigned rt = (unsigned)(T_ENC + s);
        wait_tag(cnt, rt);
        __threadfence();
        read_vec(hbuf + (rt & 1) * HSLOT + myrep * 512, tid, h_lds);
        if (s == 0) read_vec(dy + myrep * 512, tid, x_lds);
        __syncthreads();

        const float* xs = (s == 0) ? x_lds : h_lds;
        float4 vx[8], vh[8];
#pragma unroll
        for (int i = 0; i < 8; i++) {
            vx[i] = *reinterpret_cast<const float4*>(&xs[4 * lane + 256 * i]);
            vh[i] = *reinterpret_cast<const float4*>(&h_lds[4 * lane + 256 * i]);
        }

        float d[6];
#pragma unroll
        for (int g = 0; g < 6; g++) {
            float a0 = 0.f, a1 = 0.f, a2 = 0.f, a3 = 0.f;
#pragma unroll
            for (int i = 0; i < 8; i++) {
                unsigned u0 = Wd[g][i][0], u1 = Wd[g][i][1];
                float4 v4 = (g < 3) ? vx[i] : vh[i];
                a0 += __uint_as_float(u0 << 16) * v4.x;
                a1 += __uint_as_float(u0 & 0xffff0000u) * v4.y;
                a2 += __uint_as_float(u1 << 16) * v4.z;
                a3 += __uint_as_float(u1 & 0xffff0000u) * v4.w;
            }
            d[g] = (a0 + a1) + (a2 + a3);
        }
#pragma unroll
        for (int m = 1; m < 64; m <<= 1) {
#pragma unroll
            for (int g = 0; g < 6; g++) d[g] += __shfl_xor(d[g], m);
        }

        if (lane == 0) {
            float r = sigm(d[0] + dbih[wave] + d[3] + dbhh[wave]);
            float z = sigm(d[1] + dbih[8 + wave] + d[4] + dbhh[8 + wave]);
            float c = tanh_f(d[2] + dbih[16 + wave] +
                             r * (d[5] + dbhh[16 + wave]));
            float hp = (1.f - z) * c + z * hcar;
            hcar = hp;
            hy_l[wave] = hp;
            hstore[s * HID + j] = __float2half(hp);  // off-path
        }
        __syncthreads();
        if (wave == 0 && s < F_DEC - 1) {  // tag 456 consumed by no one: skip
            if (lane < 8) {
                int r = lane >> 1, b = lane & 1;
                u64 v = pk4(hy_l[4 * b], hy_l[4 * b + 1], hy_l[4 * b + 2],
                            hy_l[4 * b + 3]);
                tst(hbuf + ((rt + 1) & 1) * HSLOT + r * 512 + wg * 2 + b, v);
            }
            __threadfence();
            if (lane == 0)
                __hip_atomic_fetch_add(mycnt, 1ull, __ATOMIC_RELAXED,
                                       __HIP_MEMORY_SCOPE_AGENT);
        }
    }
}

__global__ void sird_k(const float* __restrict__ sird, const float* __restrict__ Wa,
                       const float* __restrict__ ba, const int* __restrict__ ts_p,
                       const __half* __restrict__ hstore, float* __restrict__ out) {
    __shared__ float bpre[96];
    int wave = threadIdx.x >> 6, lane = threadIdx.x & 63;
    const float4* wa4 = (const float4*)Wa;
    for (int s = wave; s < F_DEC; s += 8) {
        const uint4* hr = (const uint4*)(hstore + (size_t)s * HID);
        float acc = 0.f;
#pragma unroll
        for (int m = 0; m < 4; m++) {
            uint4 hh = hr[lane + 64 * m];
            float4 w0 = wa4[2 * (lane + 64 * m)];
            float4 w1 = wa4[2 * (lane + 64 * m) + 1];
            float2 f;
            f = __half22float2(*(__half2*)&hh.x);
            acc += w0.x * f.x + w0.y * f.y;
            f = __half22float2(*(__half2*)&hh.y);
            acc += w0.z * f.x + w0.w * f.y;
            f = __half22float2(*(__half2*)&hh.z);
            acc += w1.x * f.x + w1.y * f.y;
            f = __half22float2(*(__half2*)&hh.w);
            acc += w1.z * f.x + w1.w * f.y;
        }
#pragma unroll
        for (int m = 1; m < 64; m <<= 1) acc += __shfl_xor(acc, m);
        if (lane == 0) bpre[s] = acc;
    }
    __syncthreads();
    if (threadIdx.x == 0) {
        float s = sird[0], i = sird[1], r = sird[2], d = sird[3], n = sird[4];
        float bl = 0.f;
        for (int t = 0; t < F_DEC; t++) {
            float b = 1.f / (1.f + expf(-(bpre[t] + ba[0])));
            bl = b;
            float si = s * i * b / n, ir = i * 0.05f, id = i * 0.01f;
            s -= si;
            i += si - ir - id;
            r += ir;
            d += id;
        }
        int ts = ts_p[0];
        float* foo = out + 5;
        for (int t = 0; t < ts - 1; t++) {
            float si = s * i * bl / n, ir = i * 0.05f, id = i * 0.01f;
            s -= si;
            i += si - ir - id;
            r += ir;
            d += id;
            foo[t * 5 + 0] = s;
            foo[t * 5 + 1] = i;
            foo[t * 5 + 2] = r;
            foo[t * 5 + 3] = d;
            foo[t * 5 + 4] = n;
        }
        out[0] = s;
        out[1] = i;
        out[2] = r;
        out[3] = d;
        out[4] = n;
    }
}

extern "C" void kernel_launch(void* const* d_in, const int* in_sizes, int n_in,
                              void* d_out, int out_size, void* d_ws, size_t ws_size,
                              hipStream_t stream) {
    const float* hu = (const float*)d_in[0];
    const float* sird = (const float*)d_in[1];
    const int* ts = (const int*)d_in[2];
    const float* Wb = (const float*)d_in[3];
    const float* bb = (const float*)d_in[4];
    const float* eWih = (const float*)d_in[5];
    const float* eWhh = (const float*)d_in[6];
    const float* eBih = (const float*)d_in[7];
    const float* eBhh = (const float*)d_in[8];
    const float* dWih = (const float*)d_in[9];
    const float* dWhh = (const float*)d_in[10];
    const float* dBih = (const float*)d_in[11];
    const float* dBhh = (const float*)d_in[12];
    const float* Wa = (const float*)d_in[13];
    const float* ba = (const float*)d_in[14];

    float* wsf = (float*)d_ws;
    float* p = wsf + WS_P;
    float* q = wsf + WS_Q;
    u64* cnt = (u64*)(wsf + WS_CNT);
    u64* hbuf = (u64*)(wsf + WS_HBUF);
    u64* dy = (u64*)(wsf + WS_DX0);
    __half* hstore = (__half*)(wsf + WS_HST);

    hipLaunchKernelGGL(prep_pq, dim3(6144 / 4), dim3(256), 0, stream, eWih, Wb, bb,
                       eBih, p, q, cnt);
    hipLaunchKernelGGL(persist, dim3(NWG), dim3(NTH), 0, stream, hu, eWhh, eBhh,
                       dWih, dWhh, dBih, dBhh, p, q, cnt, hbuf, dy, hstore);
    hipLaunchKernelGGL(sird_k, dim3(1), dim3(NTH), 0, stream, sird, Wa, ba, ts,
                       hstore, (float*)d_out);
}

// Round 7
// 3846.080 us; speedup vs baseline: 5.2752x; 5.2752x over previous
//
#include <hip/hip_runtime.h>
#include <hip/hip_fp16.h>
#include <cstdint>
#include <cstddef>

// ---------------------------------------------------------------------------
// EnDeModel: GRU encoder (365 steps) -> GRU decoder (90 steps) -> SIRD rollout
// Persistent-grid: 256 WGs x 512 threads (8 waves). Wave w of WG g owns hidden
// unit j = g*8+w (3 enc fp32 rows / 6 dec bf16 rows in registers; gates done
// in-wave).
//
// Cross-WG handoff (R12): u64 = {tag32 | fp16 h[2i+1] | fp16 h[2i]} -> 1024
// words, 8 REPLICA buffers, each WG polls replica (wg&7) -- R5-proven
// transport, UNCHANGED write side (wave0 lanes 0-31 store 4 packed contiguous
// u64 x 8 replicas; R9 proved scatter fatal, R10 proved more fan-out fatal).
// R12: ONLY WAVE 0 POLLS. Lane L sticky-polls its 16 contiguous words
// (= 2 whole 64B lines; no line shared between lanes), unpacks to LDS with a
// bank-staggered rotation, then the step barrier releases waves 1-7 (which
// issue ZERO memory traffic while sleeping at s_barrier). Per-line readers:
// 32 lanes (1/WG) instead of 256; total poll requests /8. Ledger: R5 (/8
// readers) -30%; R7 (fewer req) neutral; R10 (extra fan-out) worse; R11
// (fences+atomics) 12x worse => reader pile-up per line is THE lever, and
// this is its clean /8 with no write-side cost.
// Data IS the signal: no flags, no fences, relaxed agent-scope atomics only.
// Depth-2 ring safe: tag t+2 write requires wave0 polled all t+1 => all WGs
// stored t+1 => all passed the t-step barrier => no reader of slot-t remains.
// Tags 1..456 never collide with 0xAA poison.
// History: R6 XCD relay X; R7 sticky ~; R9 scatter XX; R10 16-rep X; R11
// counter-gate XXX (fences).
// ---------------------------------------------------------------------------

#define HID   2048
#define T_ENC 365
#define F_DEC 90
#define NWG   256
#define NTH   512
#define SLOT  8192   // u64s per ring slot (8 replicas x 1024)

// ws layout (4-byte units)
#define WS_P    0        // p[6144]
#define WS_Q    6144     // q[6144]
#define WS_HBUF 12288    // u64 hbuf[2][8][1024]  (tagged fp16-pair ring)
#define WS_DX0  45056    // u64 dx0[8][1024]      (tagged raw y, replicated)
#define WS_HST  61440    // __half hstore[90][2048]

typedef unsigned long long u64;

__device__ __forceinline__ float sigm(float x) {
    return 1.0f / (1.0f + __expf(-x));
}
__device__ __forceinline__ float tanh_f(float x) {
    return 1.0f - 2.0f / (1.0f + __expf(2.0f * x));
}
__device__ __forceinline__ unsigned bf16rne(float f) {
    unsigned x = __float_as_uint(f);
    return (x + 0x7fffu + ((x >> 16) & 1u)) >> 16;
}
__device__ __forceinline__ unsigned packbf(float lo, float hi) {
    return bf16rne(lo) | (bf16rne(hi) << 16);
}

__device__ __forceinline__ u64 tld(const u64* p) {
    return __hip_atomic_load((u64*)p, __ATOMIC_RELAXED, __HIP_MEMORY_SCOPE_AGENT);
}
__device__ __forceinline__ void tst(u64* p, u64 v) {
    __hip_atomic_store(p, v, __ATOMIC_RELAXED, __HIP_MEMORY_SCOPE_AGENT);
}
// {tag | fp16(hi)<<16 | fp16(lo)} ; lo -> element 2i, hi -> element 2i+1
__device__ __forceinline__ u64 mk16(unsigned tag, float lo, float hi) {
    unsigned pk = (unsigned)__half_as_ushort(__float2half(lo)) |
                  ((unsigned)__half_as_ushort(__float2half(hi)) << 16);
    return ((u64)tag << 32) | (u64)pk;
}

// Wave-0-only sticky poll: lane L owns 16 contiguous words (2 whole 64B
// lines). Unpack into lds[2048] with rotation (i=(lane+k)&15) so concurrent
// LDS float2 stores spread across bank pairs (4-way max, ~free per m136).
__device__ __forceinline__ void poll_w0(const u64* __restrict__ rep,
                                        unsigned tag, int lane,
                                        float* __restrict__ lds) {
    const u64* base = rep + lane * 16;
    u64 x[16];
    unsigned miss = 0xffffu;
#pragma unroll
    for (int i = 0; i < 16; i++) {
        x[i] = tld(base + i);
        if ((unsigned)(x[i] >> 32) == tag) miss &= ~(1u << i);
    }
    while (__ballot(miss == 0u) != ~0ull) {
#pragma unroll
        for (int i = 0; i < 16; i++) {
            if (miss & (1u << i)) {
                x[i] = tld(base + i);
                if ((unsigned)(x[i] >> 32) == tag) miss &= ~(1u << i);
            }
        }
    }
#pragma unroll
    for (int k = 0; k < 16; k++) {
        int i = (lane + k) & 15;
        unsigned lo = (unsigned)x[i];
        *(float2*)(lds + 32 * lane + 2 * i) = __half22float2(*(__half2*)&lo);
    }
}

// p[r] = enc_Wih[r,:] @ Wb ; q[r] = enc_Wih[r,:] @ bb + enc_bih[r]
__global__ void prep_pq(const float* __restrict__ Wih, const float* __restrict__ Wb,
                        const float* __restrict__ bb, const float* __restrict__ bih,
                        float* __restrict__ p, float* __restrict__ q) {
    int wave = threadIdx.x >> 6, lane = threadIdx.x & 63;
    int row = blockIdx.x * 4 + wave;
    const float* wr = Wih + (size_t)row * HID;
    float ap = 0.f, aq = 0.f;
    for (int k = lane; k < HID; k += 64) {
        float w = wr[k];
        ap += w * Wb[k];
        aq += w * bb[k];
    }
#pragma unroll
    for (int m = 1; m < 64; m <<= 1) {
        ap += __shfl_xor(ap, m);
        aq += __shfl_xor(aq, m);
    }
    if (lane == 0) {
        p[row] = ap;
        q[row] = aq + bih[row];
    }
}

__global__ __launch_bounds__(NTH, 1) void persist(
    const float* __restrict__ hu, const float* __restrict__ encWhh,
    const float* __restrict__ encBhh, const float* __restrict__ decWih,
    const float* __restrict__ decWhh, const float* __restrict__ decBih,
    const float* __restrict__ decBhh, const float* __restrict__ p,
    const float* __restrict__ q, u64* hbuf, u64* dx0, __half* hstore) {
    const int wg = blockIdx.x, tid = threadIdx.x;
    const int wave = tid >> 6, lane = tid & 63;
    const int j = wg * 8 + wave;
    const int myrep = wg & 7;  // ~XCD by dispatch round-robin; any error only
                               // changes which 32-WG group shares a replica.

    __shared__ float h_lds[HID], x_lds[HID];
    __shared__ float hs_l[8], hy_l[8];
    __shared__ float p_l[24], q_l[24], ebhh[24], dbih[24], dbhh[24];
    __shared__ float u_l[T_ENC];

    // --- LDS preloads (once) ---
    for (int idx = tid; idx < T_ENC; idx += NTH) u_l[idx] = hu[idx];
    if (tid < 24) {
        int g = tid >> 3, jj = tid & 7;
        int r = g * HID + wg * 8 + jj;
        p_l[tid] = p[r];
        q_l[tid] = q[r];
        ebhh[tid] = encBhh[r];
        dbih[tid] = decBih[r];
        dbhh[tid] = decBhh[r];
    }

    // --- encoder Whh rows for unit j -> fp32 registers (3 rows/wave) ---
    float4 We[3][8];
#pragma unroll
    for (int g = 0; g < 3; g++) {
        const float* base = encWhh + (size_t)(g * HID + j) * HID;
#pragma unroll
        for (int i = 0; i < 8; i++)
            We[g][i] = *reinterpret_cast<const float4*>(base + 4 * lane + 256 * i);
    }

    // =========================== encoder: 365 steps =========================
    for (int t = 0; t < T_ENC; t++) {
        if (t == 0) {
            for (int idx = tid; idx < HID; idx += NTH) h_lds[idx] = 0.f;
        } else if (wave == 0) {
            poll_w0(hbuf + (t & 1) * SLOT + myrep * 1024, (unsigned)t, lane,
                    h_lds);
        }
        __syncthreads();

        float4 hreg[8];
#pragma unroll
        for (int i = 0; i < 8; i++)
            hreg[i] = *reinterpret_cast<const float4*>(&h_lds[4 * lane + 256 * i]);

        float v0, v1, v2;
        {
            float a0 = 0.f, a1 = 0.f, a2 = 0.f, a3 = 0.f;
            float b0 = 0.f, b1 = 0.f, b2 = 0.f, b3 = 0.f;
            float c0 = 0.f, c1 = 0.f, c2 = 0.f, c3 = 0.f;
#pragma unroll
            for (int i = 0; i < 8; i++) {
                float4 h4 = hreg[i];
                float4 wr_ = We[0][i], wz_ = We[1][i], wc_ = We[2][i];
                a0 += wr_.x * h4.x; a1 += wr_.y * h4.y;
                a2 += wr_.z * h4.z; a3 += wr_.w * h4.w;
                b0 += wz_.x * h4.x; b1 += wz_.y * h4.y;
                b2 += wz_.z * h4.z; b3 += wz_.w * h4.w;
                c0 += wc_.x * h4.x; c1 += wc_.y * h4.y;
                c2 += wc_.z * h4.z; c3 += wc_.w * h4.w;
            }
            v0 = (a0 + a1) + (a2 + a3);
            v1 = (b0 + b1) + (b2 + b3);
            v2 = (c0 + c1) + (c2 + c3);
        }
#pragma unroll
        for (int m = 1; m < 64; m <<= 1) {
            v0 += __shfl_xor(v0, m);
            v1 += __shfl_xor(v1, m);
            v2 += __shfl_xor(v2, m);
        }

        if (lane == 0) {
            float u = u_l[t];
            float gir = u * p_l[wave] + q_l[wave];
            float giz = u * p_l[8 + wave] + q_l[8 + wave];
            float gic = u * p_l[16 + wave] + q_l[16 + wave];
            float r = sigm(gir + v0 + ebhh[wave]);
            float z = sigm(giz + v1 + ebhh[8 + wave]);
            float c = tanh_f(gic + r * (v2 + ebhh[16 + wave]));
            float hp = (1.f - z) * c + z * h_lds[j];
            hs_l[wave] = sigm(hp);
            hy_l[wave] = hp;
        }
        __syncthreads();
        if (wave == 0 && lane < 32) {
            int i = lane & 3, r = lane >> 2;
            u64 v = mk16((unsigned)(t + 1), hs_l[2 * i], hs_l[2 * i + 1]);
            tst(hbuf + ((t + 1) & 1) * SLOT + r * 1024 + wg * 4 + i, v);
            if (t == T_ENC - 1) {
                u64 y = mk16((unsigned)T_ENC, hy_l[2 * i], hy_l[2 * i + 1]);
                tst(dx0 + r * 1024 + wg * 4 + i, y);
            }
        }
    }

    // --- decoder Wih+Whh rows for unit j -> packed bf16 (6 rows/wave) ---
    unsigned Wd[6][8][2];
#pragma unroll
    for (int g = 0; g < 6; g++) {
        const float* src = (g < 3)
            ? decWih + (size_t)(g * HID + j) * HID
            : decWhh + (size_t)((g - 3) * HID + j) * HID;
#pragma unroll
        for (int i = 0; i < 8; i++) {
            float4 w = *reinterpret_cast<const float4*>(src + 4 * lane + 256 * i);
            Wd[g][i][0] = packbf(w.x, w.y);
            Wd[g][i][1] = packbf(w.z, w.w);
        }
    }

    // =========================== decoder: 90 steps ==========================
    for (int s = 0; s < F_DEC; s++) {
        unsigned rt = (unsigned)(T_ENC + s);
        if (wave == 0) {
            poll_w0(hbuf + (rt & 1) * SLOT + myrep * 1024, rt, lane, h_lds);
            if (s == 0)
                poll_w0(dx0 + myrep * 1024, (unsigned)T_ENC, lane, x_lds);
        }
        __syncthreads();

        const float* xs = (s == 0) ? x_lds : h_lds;
        float4 vx[8], vh[8];
#pragma unroll
        for (int i = 0; i < 8; i++) {
            vx[i] = *reinterpret_cast<const float4*>(&xs[4 * lane + 256 * i]);
            vh[i] = *reinterpret_cast<const float4*>(&h_lds[4 * lane + 256 * i]);
        }

        float d[6];
#pragma unroll
        for (int g = 0; g < 6; g++) {
            float a0 = 0.f, a1 = 0.f, a2 = 0.f, a3 = 0.f;
#pragma unroll
            for (int i = 0; i < 8; i++) {
                unsigned u0 = Wd[g][i][0], u1 = Wd[g][i][1];
                float4 v4 = (g < 3) ? vx[i] : vh[i];
                a0 += __uint_as_float(u0 << 16) * v4.x;
                a1 += __uint_as_float(u0 & 0xffff0000u) * v4.y;
                a2 += __uint_as_float(u1 << 16) * v4.z;
                a3 += __uint_as_float(u1 & 0xffff0000u) * v4.w;
            }
            d[g] = (a0 + a1) + (a2 + a3);
        }
#pragma unroll
        for (int m = 1; m < 64; m <<= 1) {
#pragma unroll
            for (int g = 0; g < 6; g++) d[g] += __shfl_xor(d[g], m);
        }

        if (lane == 0) {
            float r = sigm(d[0] + dbih[wave] + d[3] + dbhh[wave]);
            float z = sigm(d[1] + dbih[8 + wave] + d[4] + dbhh[8 + wave]);
            float c = tanh_f(d[2] + dbih[16 + wave] +
                             r * (d[5] + dbhh[16 + wave]));
            float hp = (1.f - z) * c + z * h_lds[j];
            hy_l[wave] = hp;
            hstore[s * HID + j] = __float2half(hp);  // off-path
        }
        __syncthreads();
        if (wave == 0 && lane < 32) {
            int i = lane & 3, r = lane >> 2;
            u64 v = mk16(rt + 1, hy_l[2 * i], hy_l[2 * i + 1]);
            tst(hbuf + ((rt + 1) & 1) * SLOT + r * 1024 + wg * 4 + i, v);
        }
    }
}

__global__ void sird_k(const float* __restrict__ sird, const float* __restrict__ Wa,
                       const float* __restrict__ ba, const int* __restrict__ ts_p,
                       const __half* __restrict__ hstore, float* __restrict__ out) {
    __shared__ float bpre[96];
    int wave = threadIdx.x >> 6, lane = threadIdx.x & 63;
    const float4* wa4 = (const float4*)Wa;
    for (int s = wave; s < F_DEC; s += 8) {
        const uint4* hr = (const uint4*)(hstore + (size_t)s * HID);
        float acc = 0.f;
#pragma unroll
        for (int m = 0; m < 4; m++) {
            uint4 hh = hr[lane + 64 * m];
            float4 w0 = wa4[2 * (lane + 64 * m)];
            float4 w1 = wa4[2 * (lane + 64 * m) + 1];
            float2 f;
            f = __half22float2(*(__half2*)&hh.x);
            acc += w0.x * f.x + w0.y * f.y;
            f = __half22float2(*(__half2*)&hh.y);
            acc += w0.z * f.x + w0.w * f.y;
            f = __half22float2(*(__half2*)&hh.z);
            acc += w1.x * f.x + w1.y * f.y;
            f = __half22float2(*(__half2*)&hh.w);
            acc += w1.z * f.x + w1.w * f.y;
        }
#pragma unroll
        for (int m = 1; m < 64; m <<= 1) acc += __shfl_xor(acc, m);
        if (lane == 0) bpre[s] = acc;
    }
    __syncthreads();
    if (threadIdx.x == 0) {
        float s = sird[0], i = sird[1], r = sird[2], d = sird[3], n = sird[4];
        float bl = 0.f;
        for (int t = 0; t < F_DEC; t++) {
            float b = 1.f / (1.f + expf(-(bpre[t] + ba[0])));
            bl = b;
            float si = s * i * b / n, ir = i * 0.05f, id = i * 0.01f;
            s -= si;
            i += si - ir - id;
            r += ir;
            d += id;
        }
        int ts = ts_p[0];
        float* foo = out + 5;
        for (int t = 0; t < ts - 1; t++) {
            float si = s * i * bl / n, ir = i * 0.05f, id = i * 0.01f;
            s -= si;
            i += si - ir - id;
            r += ir;
            d += id;
            foo[t * 5 + 0] = s;
            foo[t * 5 + 1] = i;
            foo[t * 5 + 2] = r;
            foo[t * 5 + 3] = d;
            foo[t * 5 + 4] = n;
        }
        out[0] = s;
        out[1] = i;
        out[2] = r;
        out[3] = d;
        out[4] = n;
    }
}

extern "C" void kernel_launch(void* const* d_in, const int* in_sizes, int n_in,
                              void* d_out, int out_size, void* d_ws, size_t ws_size,
                              hipStream_t stream) {
    const float* hu = (const float*)d_in[0];
    const float* sird = (const float*)d_in[1];
    const int* ts = (const int*)d_in[2];
    const float* Wb = (const float*)d_in[3];
    const float* bb = (const float*)d_in[4];
    const float* eWih = (const float*)d_in[5];
    const float* eWhh = (const float*)d_in[6];
    const float* eBih = (const float*)d_in[7];
    const float* eBhh = (const float*)d_in[8];
    const float* dWih = (const float*)d_in[9];
    const float* dWhh = (const float*)d_in[10];
    const float* dBih = (const float*)d_in[11];
    const float* dBhh = (const float*)d_in[12];
    const float* Wa = (const float*)d_in[13];
    const float* ba = (const float*)d_in[14];

    float* wsf = (float*)d_ws;
    float* p = wsf + WS_P;
    float* q = wsf + WS_Q;
    u64* hbuf = (u64*)(wsf + WS_HBUF);
    u64* dx0 = (u64*)(wsf + WS_DX0);
    __half* hstore = (__half*)(wsf + WS_HST);

    hipLaunchKernelGGL(prep_pq, dim3(6144 / 4), dim3(256), 0, stream, eWih, Wb, bb,
                       eBih, p, q);
    hipLaunchKernelGGL(persist, dim3(NWG), dim3(NTH), 0, stream, hu, eWhh, eBhh,
                       dWih, dWhh, dBih, dBhh, p, q, hbuf, dx0, hstore);
    hipLaunchKernelGGL(sird_k, dim3(1), dim3(NTH), 0, stream, sird, Wa, ba, ts,
                       hstore, (float*)d_out);
}

// Round 8
// 2633.699 us; speedup vs baseline: 7.7035x; 1.4603x over previous
//
#include <hip/hip_runtime.h>
#include <hip/hip_fp16.h>
#include <cstdint>
#include <cstddef>

// ---------------------------------------------------------------------------
// EnDeModel: GRU encoder (365 steps) -> GRU decoder (90 steps) -> SIRD rollout
// SINGLE persistent kernel: 256 WGs x 512 threads (8 waves). Wave w of WG g
// owns hidden unit j = g*8+w (3 enc fp32 rows / 6 dec bf16 rows in registers;
// gates done in-wave).
//
// Cross-WG handoff: R5 transport, UNTOUCHED (beat 6 structured attacks:
// R6 XCD relay X, R7 sticky ~, R9 scatter XX, R10 16-replica X, R11
// counter-gate XXX, R12 wave0-poll XX de-coalesced). u64 = {tag32 | fp16
// h[2i+1] | fp16 h[2i]} -> 1024 words, 8 REPLICAS; each WG polls replica
// (wg&7), all 512 threads, coalesced; writer: waves drop h into LDS, one
// barrier, wave0 lanes 0-31 store 4 packed contiguous u64 x 8 replicas.
// Data IS the signal: no flags, no fences, relaxed agent-scope atomics.
// Depth-2 ring safe; tags 1..456 never collide with 0xAA poison.
//
// R13 (this round): fold the two side kernels into persist.
//  - prep_pq folded: each WG computes its own 24 p/q rows at startup (same
//    total eWih volume, ~2us, deletes a launch+gap).
//  - sird_k folded: wg0-wave0 keeps Wa in 8 float4 regs; at decoder step s
//    computes bpre[s-1] = Wa . hp_{s-1} from its vh regs (~100cy/step on the
//    gating WG). After the loop wg0 polls tag 456 (stored by ALL WGs -- the
//    proven mechanism) for hp_89 -> last beta; thread 0 runs the serial SIRD
//    rollout and writes out. Deletes hstore traffic + a launch+gap.
// Total was 1795.6us vs persist 1638us => ~158us of side-kernel/launch
// overhead targeted here.
// ---------------------------------------------------------------------------

#define HID   2048
#define T_ENC 365
#define F_DEC 90
#define NWG   256
#define NTH   512
#define SLOT  8192   // u64s per ring slot (8 replicas x 1024)

// ws layout (4-byte units) -- hbuf/dx0 kept at the proven offsets
#define WS_HBUF 12288    // u64 hbuf[2][8][1024]  (tagged fp16-pair ring)
#define WS_DX0  45056    // u64 dx0[8][1024]      (tagged raw y, replicated)

typedef unsigned long long u64;

__device__ __forceinline__ float sigm(float x) {
    return 1.0f / (1.0f + __expf(-x));
}
__device__ __forceinline__ float tanh_f(float x) {
    return 1.0f - 2.0f / (1.0f + __expf(2.0f * x));
}
__device__ __forceinline__ unsigned bf16rne(float f) {
    unsigned x = __float_as_uint(f);
    return (x + 0x7fffu + ((x >> 16) & 1u)) >> 16;
}
__device__ __forceinline__ unsigned packbf(float lo, float hi) {
    return bf16rne(lo) | (bf16rne(hi) << 16);
}

__device__ __forceinline__ u64 tld(const u64* p) {
    return __hip_atomic_load((u64*)p, __ATOMIC_RELAXED, __HIP_MEMORY_SCOPE_AGENT);
}
__device__ __forceinline__ void tst(u64* p, u64 v) {
    __hip_atomic_store(p, v, __ATOMIC_RELAXED, __HIP_MEMORY_SCOPE_AGENT);
}
// {tag | fp16(hi)<<16 | fp16(lo)} ; lo -> element 2i, hi -> element 2i+1
__device__ __forceinline__ u64 mk16(unsigned tag, float lo, float hi) {
    unsigned pk = (unsigned)__half_as_ushort(__float2half(lo)) |
                  ((unsigned)__half_as_ushort(__float2half(hi)) << 16);
    return ((u64)tag << 32) | (u64)pk;
}

// Poll 1024 paired u64s in our replica; unpack payloads into lds[2048].
__device__ __forceinline__ void poll_to_lds(const u64* __restrict__ rep,
                                            unsigned tag, int tid,
                                            float* __restrict__ lds) {
    const u64* p0 = rep + tid;
    const u64* p1 = rep + 512 + tid;
    u64 x0, x1;
    while (true) {
        x0 = tld(p0);
        x1 = tld(p1);
        bool ok = ((unsigned)(x0 >> 32) == tag) & ((unsigned)(x1 >> 32) == tag);
        if (__ballot(ok) == ~0ull) break;
    }
    unsigned lo0 = (unsigned)x0, lo1 = (unsigned)x1;
    float2 f0 = __half22float2(*(__half2*)&lo0);
    float2 f1 = __half22float2(*(__half2*)&lo1);
    *(float2*)(lds + 2 * tid) = f0;
    *(float2*)(lds + 1024 + 2 * tid) = f1;
}

__global__ __launch_bounds__(NTH, 1) void persist(
    const float* __restrict__ hu, const float* __restrict__ sird,
    const int* __restrict__ ts_p, const float* __restrict__ Wb,
    const float* __restrict__ bb, const float* __restrict__ encWih,
    const float* __restrict__ encWhh, const float* __restrict__ encBih,
    const float* __restrict__ encBhh, const float* __restrict__ decWih,
    const float* __restrict__ decWhh, const float* __restrict__ decBih,
    const float* __restrict__ decBhh, const float* __restrict__ Wa,
    const float* __restrict__ ba, u64* hbuf, u64* dx0,
    float* __restrict__ out) {
    const int wg = blockIdx.x, tid = threadIdx.x;
    const int wave = tid >> 6, lane = tid & 63;
    const int j = wg * 8 + wave;
    const int myrep = wg & 7;  // ~XCD by dispatch round-robin; any error only
                               // changes which 32-WG group shares a replica.

    __shared__ float h_lds[HID], x_lds[HID];
    __shared__ float hs_l[8], hy_l[8];
    __shared__ float p_l[24], q_l[24], ebhh[24], dbih[24], dbhh[24];
    __shared__ float u_l[T_ENC];
    __shared__ float bpre_l[F_DEC];

    // --- LDS preloads (once) ---
    for (int idx = tid; idx < T_ENC; idx += NTH) u_l[idx] = hu[idx];
    if (tid < 24) {
        int g = tid >> 3, jj = tid & 7;
        int r = g * HID + wg * 8 + jj;
        ebhh[tid] = encBhh[r];
        dbih[tid] = decBih[r];
        dbhh[tid] = decBhh[r];
    }

    // --- folded prep_pq: this wave computes p/q for its 3 enc rows ---
    // p[r] = encWih[r,:] @ Wb ; q[r] = encWih[r,:] @ bb + encBih[r]
    {
        float ap[3], aq[3];
#pragma unroll
        for (int g = 0; g < 3; g++) {
            const float* wr = encWih + (size_t)(g * HID + j) * HID;
            float a = 0.f, b = 0.f;
            for (int k = lane; k < HID; k += 64) {
                float w = wr[k];
                a += w * Wb[k];
                b += w * bb[k];
            }
            ap[g] = a;
            aq[g] = b;
        }
#pragma unroll
        for (int m = 1; m < 64; m <<= 1) {
#pragma unroll
            for (int g = 0; g < 3; g++) {
                ap[g] += __shfl_xor(ap[g], m);
                aq[g] += __shfl_xor(aq[g], m);
            }
        }
        if (lane == 0) {
#pragma unroll
            for (int g = 0; g < 3; g++) {
                p_l[g * 8 + wave] = ap[g];
                q_l[g * 8 + wave] = aq[g] + encBih[g * HID + j];
            }
        }
    }

    // --- encoder Whh rows for unit j -> fp32 registers (3 rows/wave) ---
    float4 We[3][8];
#pragma unroll
    for (int g = 0; g < 3; g++) {
        const float* base = encWhh + (size_t)(g * HID + j) * HID;
#pragma unroll
        for (int i = 0; i < 8; i++)
            We[g][i] = *reinterpret_cast<const float4*>(base + 4 * lane + 256 * i);
    }

    // =========================== encoder: 365 steps =========================
    for (int t = 0; t < T_ENC; t++) {
        if (t == 0) {
            for (int idx = tid; idx < HID; idx += NTH) h_lds[idx] = 0.f;
        } else {
            poll_to_lds(hbuf + (t & 1) * SLOT + myrep * 1024, (unsigned)t, tid,
                        h_lds);
        }
        __syncthreads();

        float4 hreg[8];
#pragma unroll
        for (int i = 0; i < 8; i++)
            hreg[i] = *reinterpret_cast<const float4*>(&h_lds[4 * lane + 256 * i]);

        float v0, v1, v2;
        {
            float a0 = 0.f, a1 = 0.f, a2 = 0.f, a3 = 0.f;
            float b0 = 0.f, b1 = 0.f, b2 = 0.f, b3 = 0.f;
            float c0 = 0.f, c1 = 0.f, c2 = 0.f, c3 = 0.f;
#pragma unroll
            for (int i = 0; i < 8; i++) {
                float4 h4 = hreg[i];
                float4 wr_ = We[0][i], wz_ = We[1][i], wc_ = We[2][i];
                a0 += wr_.x * h4.x; a1 += wr_.y * h4.y;
                a2 += wr_.z * h4.z; a3 += wr_.w * h4.w;
                b0 += wz_.x * h4.x; b1 += wz_.y * h4.y;
                b2 += wz_.z * h4.z; b3 += wz_.w * h4.w;
                c0 += wc_.x * h4.x; c1 += wc_.y * h4.y;
                c2 += wc_.z * h4.z; c3 += wc_.w * h4.w;
            }
            v0 = (a0 + a1) + (a2 + a3);
            v1 = (b0 + b1) + (b2 + b3);
            v2 = (c0 + c1) + (c2 + c3);
        }
#pragma unroll
        for (int m = 1; m < 64; m <<= 1) {
            v0 += __shfl_xor(v0, m);
            v1 += __shfl_xor(v1, m);
            v2 += __shfl_xor(v2, m);
        }

        if (lane == 0) {
            float u = u_l[t];
            float gir = u * p_l[wave] + q_l[wave];
            float giz = u * p_l[8 + wave] + q_l[8 + wave];
            float gic = u * p_l[16 + wave] + q_l[16 + wave];
            float r = sigm(gir + v0 + ebhh[wave]);
            float z = sigm(giz + v1 + ebhh[8 + wave]);
            float c = tanh_f(gic + r * (v2 + ebhh[16 + wave]));
            float hp = (1.f - z) * c + z * h_lds[j];
            hs_l[wave] = sigm(hp);
            hy_l[wave] = hp;
        }
        __syncthreads();
        if (wave == 0 && lane < 32) {
            int i = lane & 3, r = lane >> 2;
            u64 v = mk16((unsigned)(t + 1), hs_l[2 * i], hs_l[2 * i + 1]);
            tst(hbuf + ((t + 1) & 1) * SLOT + r * 1024 + wg * 4 + i, v);
            if (t == T_ENC - 1) {
                u64 y = mk16((unsigned)T_ENC, hy_l[2 * i], hy_l[2 * i + 1]);
                tst(dx0 + r * 1024 + wg * 4 + i, y);
            }
        }
    }

    // --- decoder Wih+Whh rows for unit j -> packed bf16 (6 rows/wave) ---
    unsigned Wd[6][8][2];
#pragma unroll
    for (int g = 0; g < 6; g++) {
        const float* src = (g < 3)
            ? decWih + (size_t)(g * HID + j) * HID
            : decWhh + (size_t)((g - 3) * HID + j) * HID;
#pragma unroll
        for (int i = 0; i < 8; i++) {
            float4 w = *reinterpret_cast<const float4*>(src + 4 * lane + 256 * i);
            Wd[g][i][0] = packbf(w.x, w.y);
            Wd[g][i][1] = packbf(w.z, w.w);
        }
    }

    // --- folded sird: wg0-wave0 keeps Wa in regs (same layout as vh) ---
    float4 waR[8];
    if (wg == 0 && wave == 0) {
#pragma unroll
        for (int i = 0; i < 8; i++)
            waR[i] = *reinterpret_cast<const float4*>(Wa + 4 * lane + 256 * i);
    }

    // =========================== decoder: 90 steps ==========================
    for (int s = 0; s < F_DEC; s++) {
        unsigned rt = (unsigned)(T_ENC + s);
        poll_to_lds(hbuf + (rt & 1) * SLOT + myrep * 1024, rt, tid, h_lds);
        if (s == 0) poll_to_lds(dx0 + myrep * 1024, (unsigned)T_ENC, tid, x_lds);
        __syncthreads();

        const float* xs = (s == 0) ? x_lds : h_lds;
        float4 vx[8], vh[8];
#pragma unroll
        for (int i = 0; i < 8; i++) {
            vx[i] = *reinterpret_cast<const float4*>(&xs[4 * lane + 256 * i]);
            vh[i] = *reinterpret_cast<const float4*>(&h_lds[4 * lane + 256 * i]);
        }

        // beta_{s-1} = Wa . hp_{s-1} (h_lds holds hp_{s-1} for s>=1)
        if (wg == 0 && wave == 0 && s > 0) {
            float acc = 0.f;
#pragma unroll
            for (int i = 0; i < 8; i++) {
                float4 w4 = waR[i], h4 = vh[i];
                acc += w4.x * h4.x + w4.y * h4.y + w4.z * h4.z + w4.w * h4.w;
            }
#pragma unroll
            for (int m = 1; m < 64; m <<= 1) acc += __shfl_xor(acc, m);
            if (lane == 0) bpre_l[s - 1] = acc;
        }

        float d[6];
#pragma unroll
        for (int g = 0; g < 6; g++) {
            float a0 = 0.f, a1 = 0.f, a2 = 0.f, a3 = 0.f;
#pragma unroll
            for (int i = 0; i < 8; i++) {
                unsigned u0 = Wd[g][i][0], u1 = Wd[g][i][1];
                float4 v4 = (g < 3) ? vx[i] : vh[i];
                a0 += __uint_as_float(u0 << 16) * v4.x;
                a1 += __uint_as_float(u0 & 0xffff0000u) * v4.y;
                a2 += __uint_as_float(u1 << 16) * v4.z;
                a3 += __uint_as_float(u1 & 0xffff0000u) * v4.w;
            }
            d[g] = (a0 + a1) + (a2 + a3);
        }
#pragma unroll
        for (int m = 1; m < 64; m <<= 1) {
#pragma unroll
            for (int g = 0; g < 6; g++) d[g] += __shfl_xor(d[g], m);
        }

        if (lane == 0) {
            float r = sigm(d[0] + dbih[wave] + d[3] + dbhh[wave]);
            float z = sigm(d[1] + dbih[8 + wave] + d[4] + dbhh[8 + wave]);
            float c = tanh_f(d[2] + dbih[16 + wave] +
                             r * (d[5] + dbhh[16 + wave]));
            float hp = (1.f - z) * c + z * h_lds[j];
            hy_l[wave] = hp;
        }
        __syncthreads();
        if (wave == 0 && lane < 32) {
            int i = lane & 3, r = lane >> 2;
            u64 v = mk16(rt + 1, hy_l[2 * i], hy_l[2 * i + 1]);
            tst(hbuf + ((rt + 1) & 1) * SLOT + r * 1024 + wg * 4 + i, v);
        }
    }

    // ================= wg0: last beta + SIRD rollout + output ===============
    if (wg == 0) {
        // tag 456 (hp_89) was stored by ALL WGs at decoder s=89 -- proven path
        poll_to_lds(hbuf + ((T_ENC + F_DEC) & 1) * SLOT + myrep * 1024,
                    (unsigned)(T_ENC + F_DEC), tid, h_lds);
        __syncthreads();
        if (wave == 0) {
            float acc = 0.f;
#pragma unroll
            for (int i = 0; i < 8; i++) {
                float4 h4 =
                    *reinterpret_cast<const float4*>(&h_lds[4 * lane + 256 * i]);
                float4 w4 = waR[i];
                acc += w4.x * h4.x + w4.y * h4.y + w4.z * h4.z + w4.w * h4.w;
            }
#pragma unroll
            for (int m = 1; m < 64; m <<= 1) acc += __shfl_xor(acc, m);
            if (lane == 0) bpre_l[F_DEC - 1] = acc;
        }
        __syncthreads();
        if (tid == 0) {
            float s = sird[0], i = sird[1], r = sird[2], d = sird[3],
                  n = sird[4];
            float ba0 = ba[0];
            float bl = 0.f;
            for (int t = 0; t < F_DEC; t++) {
                float b = 1.f / (1.f + expf(-(bpre_l[t] + ba0)));
                bl = b;
                float si = s * i * b / n, ir = i * 0.05f, id = i * 0.01f;
                s -= si;
                i += si - ir - id;
                r += ir;
                d += id;
            }
            int ts = ts_p[0];
            float* foo = out + 5;
            for (int t = 0; t < ts - 1; t++) {
                float si = s * i * bl / n, ir = i * 0.05f, id = i * 0.01f;
                s -= si;
                i += si - ir - id;
                r += ir;
                d += id;
                foo[t * 5 + 0] = s;
                foo[t * 5 + 1] = i;
                foo[t * 5 + 2] = r;
                foo[t * 5 + 3] = d;
                foo[t * 5 + 4] = n;
            }
            out[0] = s;
            out[1] = i;
            out[2] = r;
            out[3] = d;
            out[4] = n;
        }
    }
}

extern "C" void kernel_launch(void* const* d_in, const int* in_sizes, int n_in,
                              void* d_out, int out_size, void* d_ws, size_t ws_size,
                              hipStream_t stream) {
    const float* hu = (const float*)d_in[0];
    const float* sird = (const float*)d_in[1];
    const int* ts = (const int*)d_in[2];
    const float* Wb = (const float*)d_in[3];
    const float* bb = (const float*)d_in[4];
    const float* eWih = (const float*)d_in[5];
    const float* eWhh = (const float*)d_in[6];
    const float* eBih = (const float*)d_in[7];
    const float* eBhh = (const float*)d_in[8];
    const float* dWih = (const float*)d_in[9];
    const float* dWhh = (const float*)d_in[10];
    const float* dBih = (const float*)d_in[11];
    const float* dBhh = (const float*)d_in[12];
    const float* Wa = (const float*)d_in[13];
    const float* ba = (const float*)d_in[14];

    float* wsf = (float*)d_ws;
    u64* hbuf = (u64*)(wsf + WS_HBUF);
    u64* dx0 = (u64*)(wsf + WS_DX0);

    hipLaunchKernelGGL(persist, dim3(NWG), dim3(NTH), 0, stream, hu, sird, ts,
                       Wb, bb, eWih, eWhh, eBih, eBhh, dWih, dWhh, dBih, dBhh,
                       Wa, ba, hbuf, dx0, (float*)d_out);
}